// Round 3
// baseline (472.606 us; speedup 1.0000x reference)
//
#include <hip/hip_runtime.h>
#include <math.h>

#define NBV 4096
#define KNE 64
// flat float offsets in d_out: (d, dist, pos, idx) in return order
#define D_OFF    0
#define DIST_OFF (NBV*KNE)                       // 262144
#define POS_OFF  (DIST_OFF + NBV*KNE*400)        // 105119744
#define IDX_OFF  (POS_OFF + NBV*KNE*16)          // 109314048

// ws layout (floats): [0, 65536) crd5 rows, stride 16 (5 pts x 3 + pad)
//                     [65536, 81920) compact CA as float4 (stride 4)
//                     [81920, 344064) jidx as int, 64 per row
#define WS_CRD5 0
#define WS_CA4  (NBV*16)
#define WS_JIDX (NBV*20)
#define WS_FLOATS (NBV*20 + NBV*KNE)

typedef float f4v __attribute__((ext_vector_type(4)));

// float -> order-preserving uint32 (ascending float => ascending uint)
__device__ __forceinline__ unsigned int f2sort(float f) {
  unsigned int u = __float_as_uint(f);
  return (u & 0x80000000u) ? ~u : (u | 0x80000000u);
}
__device__ __forceinline__ float sort2f(unsigned int s) {
  unsigned int u = (s & 0x80000000u) ? (s & 0x7FFFFFFFu) : ~s;
  return __uint_as_float(u);
}

// q-th float4 (q in 0..3) of the 16-float crd5 row r, computed from raw crd
__device__ __forceinline__ float4 crd5_f4(const float* __restrict__ crd, int r,
                                          int q) {
  if (q < 3) return ((const float4*)crd)[r * 3 + q];
  const float4 a = ((const float4*)crd)[r * 3 + 0];
  const float4 b = ((const float4*)crd)[r * 3 + 1];
  const float4 c = ((const float4*)crd)[r * 3 + 2];
  const float bx = a.w - a.x, by = b.x - a.y, bz = b.y - a.z;   // p1-p0
  const float cx = b.z - a.w, cy = b.w - b.x, cz = c.x - b.y;   // p2-p1
  const float axv = by * cz - bz * cy;
  const float ayv = bz * cx - bx * cz;
  const float azv = bx * cy - by * cx;
  return make_float4(
      -0.58273431f * axv + 0.56802827f * bx - 0.54067466f * cx + a.w,
      -0.58273431f * ayv + 0.56802827f * by - 0.54067466f * cy + b.x,
      -0.58273431f * azv + 0.56802827f * bz - 0.54067466f * cz + b.y, 0.0f);
}

// ---------------- prep: crd -> compact crd5 (stride 16) + CA float4 --------
__global__ __launch_bounds__(256) void prep_k(const float* __restrict__ crd,
                                              float* __restrict__ ws) {
  const int r = blockIdx.x * 256 + threadIdx.x;  // 4096 threads
  const float4 a = ((const float4*)crd)[r * 3 + 0];
  const float4 b = ((const float4*)crd)[r * 3 + 1];
  const float4 c = ((const float4*)crd)[r * 3 + 2];
  const float bx = a.w - a.x, by = b.x - a.y, bz = b.y - a.z;
  const float cx = b.z - a.w, cy = b.w - b.x, cz = c.x - b.y;
  const float axv = by * cz - bz * cy;
  const float ayv = bz * cx - bx * cz;
  const float azv = bx * cy - by * cx;
  const float cbx = -0.58273431f * axv + 0.56802827f * bx - 0.54067466f * cx + a.w;
  const float cby = -0.58273431f * ayv + 0.56802827f * by - 0.54067466f * cy + b.x;
  const float cbz = -0.58273431f * azv + 0.56802827f * bz - 0.54067466f * cz + b.y;

  float4* row = (float4*)(ws + WS_CRD5 + r * 16);
  row[0] = a;
  row[1] = b;
  row[2] = c;
  row[3] = make_float4(cbx, cby, cbz, 0.0f);
  ((float4*)(ws + WS_CA4))[r] = make_float4(a.w, b.x, b.y, 0.0f);
}

// ---------------- A: top-64 selection + d/idx/pos emit ---------------------
// Sort key is f = sqrtf(dx*dx+dy*dy+dz*dz) — bit-identical arithmetic to the
// reference's norm, so near-tie ordering (index tie-break) matches jax.
// (d^2 keying is UNSAFE: distinct d^2 can round to equal d after sqrt, which
// jax treats as an index-order tie but a d^2 sort orders by value.)
__global__ __launch_bounds__(256) void selA_k(const float* __restrict__ ws,
                                              float* __restrict__ out,
                                              int* __restrict__ jidx_ws) {
  const int i = blockIdx.x;
  const int t = threadIdx.x;

  __shared__ unsigned int hist[2048];      // 8 KB
  __shared__ unsigned long long cand[512]; // 4 KB
  __shared__ int jidx[64];
  __shared__ unsigned int cnt;
  __shared__ int selbin;
  __shared__ unsigned int wsum[4];

  for (int b = t; b < 2048; b += 256) hist[b] = 0u;
  if (t == 0) cnt = 0u;
  __syncthreads();

  const float4 ci = ((const float4*)(ws + WS_CA4))[i];

  // ---- distance scan + histogram (bins of 1/16 over [0,128)) ----
  float dv[16];
#pragma unroll
  for (int s = 0; s < 16; s++) {
    const int j = t + 256 * s;
    const float4 cj = ((const float4*)(ws + WS_CA4))[j];
    const float dx = ci.x - cj.x, dy = ci.y - cj.y, dz = ci.z - cj.z;
    float f = sqrtf(dx * dx + dy * dy + dz * dz);
    if (j == i) f = -1.0f;  // diag = -1 => self is always rank 0
    dv[s] = f;
    int b = (int)(f * 16.0f);
    b = b < 0 ? 0 : (b > 2047 ? 2047 : b);
    atomicAdd(&hist[b], 1u);
  }
  __syncthreads();

  // ---- block prefix scan over 2048 bins; first bin with cum >= 64 ----
  unsigned int bc[8];
  unsigned int loc = 0;
#pragma unroll
  for (int r = 0; r < 8; r++) { bc[r] = hist[t * 8 + r]; loc += bc[r]; }
  const int lane = t & 63, wid = t >> 6;
  unsigned int x = loc;
#pragma unroll
  for (int off = 1; off < 64; off <<= 1) {
    unsigned int y = __shfl_up(x, off, 64);
    if (lane >= off) x += y;
  }
  if (lane == 63) wsum[wid] = x;
  __syncthreads();
  unsigned int woff = 0;
#pragma unroll
  for (int w = 0; w < 4; w++)
    if (w < wid) woff += wsum[w];
  unsigned int c = woff + x - loc;
#pragma unroll
  for (int r = 0; r < 8; r++) {
    if (c < 64u && c + bc[r] >= 64u) selbin = t * 8 + r;  // unique crossing
    c += bc[r];
  }
  __syncthreads();
  const int B = selbin;

  // ---- collect candidates in bins <= B (expected ~80, cap 512) ----
#pragma unroll
  for (int s = 0; s < 16; s++) {
    const float f = dv[s];
    int b = (int)(f * 16.0f);
    b = b < 0 ? 0 : (b > 2047 ? 2047 : b);
    if (b <= B) {
      const unsigned int p = atomicAdd(&cnt, 1u);
      if (p < 512u) {
        const int j = t + 256 * s;
        cand[p] = (((unsigned long long)f2sort(f)) << 32) | (unsigned int)j;
      }
    }
  }
  __syncthreads();
  unsigned int M = cnt;
  if (M > 512u) M = 512u;
  for (int p = t; p < 512; p += 256)
    if ((unsigned)p >= M) cand[p] = 0xFFFFFFFFFFFFFFFFull;

  // ---- bitonic sort, dynamic size P = next_pow2(M) in {64..512} ----
  int P = 64;
  while (P < (int)M) P <<= 1;
  for (int ksz = 2; ksz <= P; ksz <<= 1) {
    for (int jsz = ksz >> 1; jsz > 0; jsz >>= 1) {
      __syncthreads();
      if (t < (P >> 1)) {
        const int a = ((t & ~(jsz - 1)) << 1) | (t & (jsz - 1));
        const int b2 = a | jsz;
        const unsigned long long va = cand[a], vb = cand[b2];
        const bool up = ((a & ksz) == 0);
        if ((va > vb) == up) { cand[a] = vb; cand[b2] = va; }
      }
    }
  }
  __syncthreads();

  // ---- emit d, idx; jidx to LDS + ws ----
  if (t < KNE) {
    const unsigned long long key = cand[t];
    const int j = (int)(unsigned int)(key & 0xFFFFFFFFull);
    const float f = sort2f((unsigned int)(key >> 32));
    jidx[t] = j;
    jidx_ws[i * KNE + t] = j;
    out[D_OFF + i * KNE + t] = (t == 0) ? 0.0f : f;  // d[:,0] = 0
    out[IDX_OFF + i * KNE + t] = (float)j;
  }
  __syncthreads();

  // ---- pos: thread (n,g)=(t>>2,t&3) -> one coalesced float4 ----
  {
    const int n = t >> 2, g = t & 3;
    const int j = jidx[n];
    int di = i - j;
    if (di < 0) di = -di;
    const float offv = (float)di;
    const bool hi = (g & 1);
    const float fA = hi ? 0.01f                   : 1.0f;
    const float fB = hi ? 0.0031622776601683794f  : 0.31622776601683794f;
    const float fC = hi ? 0.001f                  : 0.1f;
    const float fD = hi ? 0.00031622776601683794f : 0.031622776601683791f;
    float s0, c0, s1, c1, s2, c2, s3, c3;
    sincosf(offv * fA, &s0, &c0);
    sincosf(offv * fB, &s1, &c1);
    sincosf(offv * fC, &s2, &c2);
    sincosf(offv * fD, &s3, &c3);
    f4v o;
    if (g < 2) o = (f4v){c0, c1, c2, c3};
    else       o = (f4v){s0, s1, s2, s3};
    f4v* pv = (f4v*)(out + POS_OFF) + (size_t)(i * KNE + n) * 4 + g;
    __builtin_nontemporal_store(o, pv);
  }
}

// ---------------- B: pure write-stream GRBF kernel -------------------------
__global__ __launch_bounds__(256) void distB_k(const float* __restrict__ ws,
                                               const int* __restrict__ jidx_ws,
                                               float* __restrict__ out) {
  const int i = blockIdx.x;
  const int t = threadIdx.x;

  __shared__ float rows[65 * 16];  // 4160 B
  __shared__ float dvals[1600];    // 6400 B
  __shared__ int jidx[64];

  if (t < 64) jidx[t] = jidx_ws[i * KNE + t];
  __syncthreads();

  // stage 65 crd5 rows (4 threads per row, one float4 each)
  {
    const int sr = t >> 2, qq = t & 3;
    ((float4*)rows)[sr * 4 + qq] = ((const float4*)ws)[jidx[sr] * 4 + qq];
    if (t < 4) ((float4*)rows)[64 * 4 + t] = ((const float4*)ws)[i * 4 + t];
  }
  __syncthreads();

  // 1600 pair distances into LDS
#pragma unroll
  for (int it = 0; it < 7; it++) {
    const int pid = t + 256 * it;
    if (pid < 1600) {
      const int k = pid / 25;
      const int p = pid - k * 25;
      const int p0 = p / 5;
      const int p1 = p - p0 * 5;
      const float dx = rows[64 * 16 + p0 * 3 + 0] - rows[k * 16 + p1 * 3 + 0];
      const float dy = rows[64 * 16 + p0 * 3 + 1] - rows[k * 16 + p1 * 3 + 1];
      const float dz = rows[64 * 16 + p0 * 3 + 2] - rows[k * 16 + p1 * 3 + 2];
      dvals[pid] = sqrtf(dx * dx + dy * dy + dz * dz);
    }
  }
  __syncthreads();

  // GRBF encode via exp-recurrence + nontemporal coalesced stores.
  // Within a group of 4 centers spaced s: E_{k+1} = E_k * q_k,
  // q_{k+1} = q_k * rho, q_0 = exp(2s*u - s^2), rho = exp(-2 s^2).
  const float step = 20.0f / 15.0f;
  const float TWO_S = 2.6666667f;
  const float S2 = 1.7777778f;
  const float RHO = 0.02856550f;  // exp(-2*step^2)
  f4v* dst = (f4v*)(out + DIST_OFF) + (size_t)i * 6400;
#pragma unroll
  for (int s = 0; s < 25; s++) {
    const int f4i = t + 256 * s;  // 6400 float4 per block
    const int pair = f4i >> 2;
    const float cb0 = (float)((f4i & 3) * 4) * step;
    float u = dvals[pair] - cb0;
    u = fminf(u, 16.0f);
    float e = __expf(-u * u);
    float q = __expf(fmaf(TWO_S, u, -S2));
    f4v o;
    o.x = e;
    e *= q;           o.y = e;
    q *= RHO; e *= q; o.z = e;
    q *= RHO; e *= q; o.w = e;
    __builtin_nontemporal_store(o, dst + f4i);
  }
}

// ---------------- fallback: original fused kernel (no ws) ------------------
template <bool USE_WS>
__global__ __launch_bounds__(256) void fused_k(const float* __restrict__ crd,
                                               const float* __restrict__ ws,
                                               float* __restrict__ out) {
  const int i = blockIdx.x;
  const int t = threadIdx.x;

  __shared__ float region0[2688];
  __shared__ unsigned long long cand[512];
  __shared__ int jidx[64];
  __shared__ unsigned int cnt;
  __shared__ int selbin;
  __shared__ unsigned int wsum[4];

  unsigned int* hist = (unsigned int*)region0;
  float* rows = region0;
  float* dvals = region0 + 1040;

  for (int b = t; b < 2048; b += 256) hist[b] = 0u;
  if (t == 0) cnt = 0u;
  __syncthreads();

  float cax, cay, caz;
  cax = crd[i * 12 + 3]; cay = crd[i * 12 + 4]; caz = crd[i * 12 + 5];

  float dv[16];
#pragma unroll
  for (int s = 0; s < 16; s++) {
    const int j = t + 256 * s;
    float jx = crd[j * 12 + 3], jy = crd[j * 12 + 4], jz = crd[j * 12 + 5];
    const float dx = cax - jx, dy = cay - jy, dz = caz - jz;
    float f = sqrtf(dx * dx + dy * dy + dz * dz);
    if (j == i) f = -1.0f;
    dv[s] = f;
    int b = (int)(f * 16.0f);
    b = b < 0 ? 0 : (b > 2047 ? 2047 : b);
    atomicAdd(&hist[b], 1u);
  }
  __syncthreads();

  unsigned int bc[8];
  unsigned int loc = 0;
#pragma unroll
  for (int r = 0; r < 8; r++) { bc[r] = hist[t * 8 + r]; loc += bc[r]; }
  const int lane = t & 63, wid = t >> 6;
  unsigned int x = loc;
#pragma unroll
  for (int off = 1; off < 64; off <<= 1) {
    unsigned int y = __shfl_up(x, off, 64);
    if (lane >= off) x += y;
  }
  if (lane == 63) wsum[wid] = x;
  __syncthreads();
  unsigned int woff = 0;
#pragma unroll
  for (int w = 0; w < 4; w++)
    if (w < wid) woff += wsum[w];
  unsigned int c = woff + x - loc;
#pragma unroll
  for (int r = 0; r < 8; r++) {
    if (c < 64u && c + bc[r] >= 64u) selbin = t * 8 + r;
    c += bc[r];
  }
  __syncthreads();
  const int B = selbin;

#pragma unroll
  for (int s = 0; s < 16; s++) {
    const float f = dv[s];
    int b = (int)(f * 16.0f);
    b = b < 0 ? 0 : (b > 2047 ? 2047 : b);
    if (b <= B) {
      const unsigned int p = atomicAdd(&cnt, 1u);
      if (p < 512u) {
        const int j = t + 256 * s;
        cand[p] = (((unsigned long long)f2sort(f)) << 32) | (unsigned int)j;
      }
    }
  }
  __syncthreads();
  unsigned int M = cnt;
  if (M > 512u) M = 512u;
  for (int p = t; p < 512; p += 256)
    if ((unsigned)p >= M) cand[p] = 0xFFFFFFFFFFFFFFFFull;

  int P = 64;
  while (P < (int)M) P <<= 1;
  for (int ksz = 2; ksz <= P; ksz <<= 1) {
    for (int jsz = ksz >> 1; jsz > 0; jsz >>= 1) {
      __syncthreads();
      if (t < (P >> 1)) {
        const int a = ((t & ~(jsz - 1)) << 1) | (t & (jsz - 1));
        const int b2 = a | jsz;
        const unsigned long long va = cand[a], vb = cand[b2];
        const bool up = ((a & ksz) == 0);
        if ((va > vb) == up) { cand[a] = vb; cand[b2] = va; }
      }
    }
  }
  __syncthreads();

  if (t < KNE) {
    const unsigned long long key = cand[t];
    const int j = (int)(unsigned int)(key & 0xFFFFFFFFull);
    const float f = sort2f((unsigned int)(key >> 32));
    jidx[t] = j;
    out[D_OFF + i * KNE + t] = (t == 0) ? 0.0f : f;
    out[IDX_OFF + i * KNE + t] = (float)j;
  }
  __syncthreads();

  const int sr = t >> 2, qq = t & 3;
  float4 v, v2;
  v = crd5_f4(crd, jidx[sr], qq);
  if (t < 4) v2 = crd5_f4(crd, i, t);

  {
    const int n = sr, g = qq;
    const int j = jidx[n];
    int di = i - j;
    if (di < 0) di = -di;
    const float offv = (float)di;
    const bool hi = (g & 1);
    const float fA = hi ? 0.01f                   : 1.0f;
    const float fB = hi ? 0.0031622776601683794f  : 0.31622776601683794f;
    const float fC = hi ? 0.001f                  : 0.1f;
    const float fD = hi ? 0.00031622776601683794f : 0.031622776601683791f;
    float s0, c0, s1, c1, s2, c2, s3, c3;
    sincosf(offv * fA, &s0, &c0);
    sincosf(offv * fB, &s1, &c1);
    sincosf(offv * fC, &s2, &c2);
    sincosf(offv * fD, &s3, &c3);
    f4v o;
    if (g < 2) o = (f4v){c0, c1, c2, c3};
    else       o = (f4v){s0, s1, s2, s3};
    f4v* pv = (f4v*)(out + POS_OFF) + (size_t)(i * KNE + n) * 4 + g;
    __builtin_nontemporal_store(o, pv);
  }

  ((float4*)rows)[sr * 4 + qq] = v;
  if (t < 4) ((float4*)rows)[64 * 4 + t] = v2;
  __syncthreads();

#pragma unroll
  for (int it = 0; it < 7; it++) {
    const int pid = t + 256 * it;
    if (pid < 1600) {
      const int k = pid / 25;
      const int p = pid - k * 25;
      const int p0 = p / 5;
      const int p1 = p - p0 * 5;
      const float dx = rows[64 * 16 + p0 * 3 + 0] - rows[k * 16 + p1 * 3 + 0];
      const float dy = rows[64 * 16 + p0 * 3 + 1] - rows[k * 16 + p1 * 3 + 1];
      const float dz = rows[64 * 16 + p0 * 3 + 2] - rows[k * 16 + p1 * 3 + 2];
      dvals[pid] = sqrtf(dx * dx + dy * dy + dz * dz);
    }
  }
  __syncthreads();

  const float step = 20.0f / 15.0f;
  const float TWO_S = 2.6666667f;
  const float S2 = 1.7777778f;
  const float RHO = 0.02856550f;
  f4v* dst = (f4v*)(out + DIST_OFF) + (size_t)i * 6400;
#pragma unroll
  for (int s = 0; s < 25; s++) {
    const int f4i = t + 256 * s;
    const int pair = f4i >> 2;
    const float cb0 = (float)((f4i & 3) * 4) * step;
    float u = dvals[pair] - cb0;
    u = fminf(u, 16.0f);
    float e = __expf(-u * u);
    float q = __expf(fmaf(TWO_S, u, -S2));
    f4v o;
    o.x = e;
    e *= q;           o.y = e;
    q *= RHO; e *= q; o.z = e;
    q *= RHO; e *= q; o.w = e;
    __builtin_nontemporal_store(o, dst + f4i);
  }
}

extern "C" void kernel_launch(void* const* d_in, const int* in_sizes, int n_in,
                              void* d_out, int out_size, void* d_ws, size_t ws_size,
                              hipStream_t stream) {
  const float* crd = (const float*)d_in[0];
  float* out = (float*)d_out;
  if (ws_size >= (size_t)WS_FLOATS * sizeof(float)) {
    float* ws = (float*)d_ws;
    int* jidx_ws = (int*)(ws + WS_JIDX);
    hipLaunchKernelGGL(prep_k, dim3(NBV / 256), dim3(256), 0, stream, crd, ws);
    hipLaunchKernelGGL(selA_k, dim3(NBV), dim3(256), 0, stream, ws, out,
                       jidx_ws);
    hipLaunchKernelGGL(distB_k, dim3(NBV), dim3(256), 0, stream, ws, jidx_ws,
                       out);
  } else {
    hipLaunchKernelGGL(fused_k<false>, dim3(NBV), dim3(256), 0, stream, crd,
                       (const float*)nullptr, out);
  }
}

// Round 4
// 445.385 us; speedup vs baseline: 1.0611x; 1.0611x over previous
//
#include <hip/hip_runtime.h>
#include <math.h>

#define NBV 4096
#define KNE 64
// flat float offsets in d_out: (d, dist, pos, idx) in return order
#define D_OFF    0
#define DIST_OFF (NBV*KNE)                       // 262144
#define POS_OFF  (DIST_OFF + NBV*KNE*400)        // 105119744
#define IDX_OFF  (POS_OFF + NBV*KNE*16)          // 109314048

// ws layout (floats): [0, 65536) crd5 rows, stride 16 (5 pts x 3 + pad)
//                     [65536, 81920) compact CA as float4 (stride 4)
#define WS_CRD5 0
#define WS_CA4  (NBV*16)
#define WS_FLOATS (NBV*16 + NBV*4)

typedef float f4v __attribute__((ext_vector_type(4)));

// float -> order-preserving uint32 (ascending float => ascending uint)
__device__ __forceinline__ unsigned int f2sort(float f) {
  unsigned int u = __float_as_uint(f);
  return (u & 0x80000000u) ? ~u : (u | 0x80000000u);
}
__device__ __forceinline__ float sort2f(unsigned int s) {
  unsigned int u = (s & 0x80000000u) ? (s & 0x7FFFFFFFu) : ~s;
  return __uint_as_float(u);
}

// q-th float4 (q in 0..3) of the 16-float crd5 row r, computed from raw crd
__device__ __forceinline__ float4 crd5_f4(const float* __restrict__ crd, int r,
                                          int q) {
  if (q < 3) return ((const float4*)crd)[r * 3 + q];
  const float4 a = ((const float4*)crd)[r * 3 + 0];
  const float4 b = ((const float4*)crd)[r * 3 + 1];
  const float4 c = ((const float4*)crd)[r * 3 + 2];
  const float bx = a.w - a.x, by = b.x - a.y, bz = b.y - a.z;   // p1-p0
  const float cx = b.z - a.w, cy = b.w - b.x, cz = c.x - b.y;   // p2-p1
  const float axv = by * cz - bz * cy;
  const float ayv = bz * cx - bx * cz;
  const float azv = bx * cy - by * cx;
  return make_float4(
      -0.58273431f * axv + 0.56802827f * bx - 0.54067466f * cx + a.w,
      -0.58273431f * ayv + 0.56802827f * by - 0.54067466f * cy + b.x,
      -0.58273431f * azv + 0.56802827f * bz - 0.54067466f * cz + b.y, 0.0f);
}

// ---------------- prep: crd -> compact crd5 (stride 16) + CA float4 --------
__global__ __launch_bounds__(256) void prep_k(const float* __restrict__ crd,
                                              float* __restrict__ ws) {
  const int r = blockIdx.x * 256 + threadIdx.x;  // 4096 threads
  const float4 a = ((const float4*)crd)[r * 3 + 0];
  const float4 b = ((const float4*)crd)[r * 3 + 1];
  const float4 c = ((const float4*)crd)[r * 3 + 2];
  const float bx = a.w - a.x, by = b.x - a.y, bz = b.y - a.z;
  const float cx = b.z - a.w, cy = b.w - b.x, cz = c.x - b.y;
  const float axv = by * cz - bz * cy;
  const float ayv = bz * cx - bx * cz;
  const float azv = bx * cy - by * cx;
  const float cbx = -0.58273431f * axv + 0.56802827f * bx - 0.54067466f * cx + a.w;
  const float cby = -0.58273431f * ayv + 0.56802827f * by - 0.54067466f * cy + b.x;
  const float cbz = -0.58273431f * azv + 0.56802827f * bz - 0.54067466f * cz + b.y;

  float4* row = (float4*)(ws + WS_CRD5 + r * 16);
  row[0] = a;
  row[1] = b;
  row[2] = c;
  row[3] = make_float4(cbx, cby, cbz, 0.0f);
  ((float4*)(ws + WS_CA4))[r] = make_float4(a.w, b.x, b.y, 0.0f);
}

// ---------------- fused: select top-64 + pos + grbf dist, one block/row ----
// Selection: histogram-bin threshold -> ballot-compacted candidate collect ->
// O(M^2) rank-select (replaces bitonic: ~28 fewer barrier stages). Keys are
// (f2sort(d) << 32) | j — unique, so ranks are a permutation; winners are
// ranks 0..63 in ascending (d, j) order, identical to a full sort + take-64.
template <bool USE_WS>
__global__ __launch_bounds__(256) void fused_k(const float* __restrict__ crd,
                                               const float* __restrict__ ws,
                                               float* __restrict__ out) {
  const int i = blockIdx.x;
  const int t = threadIdx.x;

  // region0 union: selection uses it as hist[2048] (8 KB);
  // dist phase reuses it as rows[65*16] (4160 B) + dvals[1600] (6400 B).
  __shared__ float region0[2688];          // 10752 B
  __shared__ unsigned long long cand[512]; // 4 KB
  __shared__ int jidx[64];
  __shared__ unsigned int cnt;
  __shared__ int selbin;
  __shared__ unsigned int wsum[4];

  unsigned int* hist = (unsigned int*)region0;
  float* rows = region0;          // [0, 1040)
  float* dvals = region0 + 1040;  // [1040, 2640)

  for (int b = t; b < 2048; b += 256) hist[b] = 0u;
  if (t == 0) cnt = 0u;
  __syncthreads();

  float cax, cay, caz;
  if (USE_WS) {
    const float4 c4 = ((const float4*)(ws + WS_CA4))[i];
    cax = c4.x; cay = c4.y; caz = c4.z;
  } else {
    cax = crd[i * 12 + 3]; cay = crd[i * 12 + 4]; caz = crd[i * 12 + 5];
  }

  // ---- distance scan + histogram (bins of 1/16 over [0,128)) ----
  float dv[16];
#pragma unroll
  for (int s = 0; s < 16; s++) {
    const int j = t + 256 * s;
    float jx, jy, jz;
    if (USE_WS) {
      const float4 c4 = ((const float4*)(ws + WS_CA4))[j];
      jx = c4.x; jy = c4.y; jz = c4.z;
    } else {
      jx = crd[j * 12 + 3]; jy = crd[j * 12 + 4]; jz = crd[j * 12 + 5];
    }
    const float dx = cax - jx, dy = cay - jy, dz = caz - jz;
    float f = sqrtf(dx * dx + dy * dy + dz * dz);
    if (j == i) f = -1.0f;  // diag = -1 => self is always rank 0
    dv[s] = f;
    int b = (int)(f * 16.0f);
    b = b < 0 ? 0 : (b > 2047 ? 2047 : b);
    atomicAdd(&hist[b], 1u);
  }
  __syncthreads();

  // ---- block prefix scan over 2048 bins; first bin with cum >= 64 ----
  unsigned int bc[8];
  unsigned int loc = 0;
#pragma unroll
  for (int r = 0; r < 8; r++) { bc[r] = hist[t * 8 + r]; loc += bc[r]; }
  const int lane = t & 63, wid = t >> 6;
  unsigned int x = loc;
#pragma unroll
  for (int off = 1; off < 64; off <<= 1) {
    unsigned int y = __shfl_up(x, off, 64);
    if (lane >= off) x += y;
  }
  if (lane == 63) wsum[wid] = x;
  __syncthreads();
  unsigned int woff = 0;
#pragma unroll
  for (int w = 0; w < 4; w++)
    if (w < wid) woff += wsum[w];
  unsigned int c = woff + x - loc;
#pragma unroll
  for (int r = 0; r < 8; r++) {
    if (c < 64u && c + bc[r] >= 64u) selbin = t * 8 + r;  // unique crossing
    c += bc[r];
  }
  __syncthreads();
  const int B = selbin;

  // ---- collect candidates in bins <= B (expected ~80, cap 512) ----
  // Ballot-compacted: one atomicAdd per wave per pass instead of one per
  // candidate. cand[] order is arbitrary; rank-select below re-orders.
  const unsigned long long lmask = (1ull << lane) - 1ull;
#pragma unroll
  for (int s = 0; s < 16; s++) {
    const float f = dv[s];
    int b = (int)(f * 16.0f);
    b = b < 0 ? 0 : (b > 2047 ? 2047 : b);
    const bool pred = (b <= B);
    const unsigned long long mask = __ballot(pred);
    unsigned int base = 0;
    if (lane == 0 && mask)
      base = atomicAdd(&cnt, (unsigned int)__popcll(mask));
    base = __shfl(base, 0, 64);
    if (pred) {
      const unsigned int p = base + (unsigned int)__popcll(mask & lmask);
      if (p < 512u) {
        const int j = t + 256 * s;
        cand[p] = (((unsigned long long)f2sort(f)) << 32) | (unsigned int)j;
      }
    }
  }
  __syncthreads();

  // ---- O(M^2) rank-select: winner r gets the (r+1)-smallest key ----
  {
    unsigned int M = cnt;
    if (M > 512u) M = 512u;
    for (int p = t; p < (int)M; p += 256) {
      const unsigned long long key = cand[p];
      int r = 0;
      for (int q = 0; q < (int)M; q++) r += (cand[q] < key);  // LDS broadcast
      if (r < KNE) {
        const int j = (int)(unsigned int)(key & 0xFFFFFFFFull);
        const float f = sort2f((unsigned int)(key >> 32));
        jidx[r] = j;
        out[D_OFF + i * KNE + r] = (r == 0) ? 0.0f : f;  // d[:,0] = 0
        out[IDX_OFF + i * KNE + r] = (float)j;
      }
    }
  }
  __syncthreads();  // jidx ready; hist region dead -> reuse as rows/dvals

  // ---- stage 65 crd5 rows (issue loads first) + pos with all 256 threads --
  const int sr = t >> 2, qq = t & 3;
  float4 v, v2;
  if (USE_WS) v = ((const float4*)ws)[jidx[sr] * 4 + qq];
  else        v = crd5_f4(crd, jidx[sr], qq);
  if (t < 4) {
    if (USE_WS) v2 = ((const float4*)ws)[i * 4 + t];
    else        v2 = crd5_f4(crd, i, t);
  }

  // pos: thread (n,g) = (t>>2, t&3) computes one float4 of neighbor n:
  //   g=0: cos(f0..f3)  g=1: cos(f4..f7)  g=2: sin(f0..f3)  g=3: sin(f4..f7)
  {
    const int n = sr, g = qq;
    const int j = jidx[n];
    int di = i - j;
    if (di < 0) di = -di;
    const float offv = (float)di;
    const bool hi = (g & 1);
    const float fA = hi ? 0.01f                   : 1.0f;
    const float fB = hi ? 0.0031622776601683794f  : 0.31622776601683794f;
    const float fC = hi ? 0.001f                  : 0.1f;
    const float fD = hi ? 0.00031622776601683794f : 0.031622776601683791f;
    float s0, c0, s1, c1, s2, c2, s3, c3;
    sincosf(offv * fA, &s0, &c0);
    sincosf(offv * fB, &s1, &c1);
    sincosf(offv * fC, &s2, &c2);
    sincosf(offv * fD, &s3, &c3);
    f4v o;
    if (g < 2) o = (f4v){c0, c1, c2, c3};
    else       o = (f4v){s0, s1, s2, s3};
    f4v* pv = (f4v*)(out + POS_OFF) + (size_t)(i * KNE + n) * 4 + g;
    __builtin_nontemporal_store(o, pv);
  }

  ((float4*)rows)[sr * 4 + qq] = v;
  if (t < 4) ((float4*)rows)[64 * 4 + t] = v2;
  __syncthreads();

  // ---- 1600 pair distances into LDS ----
#pragma unroll
  for (int it = 0; it < 7; it++) {
    const int pid = t + 256 * it;
    if (pid < 1600) {
      const int k = pid / 25;
      const int p = pid - k * 25;
      const int p0 = p / 5;
      const int p1 = p - p0 * 5;
      const float dx = rows[64 * 16 + p0 * 3 + 0] - rows[k * 16 + p1 * 3 + 0];
      const float dy = rows[64 * 16 + p0 * 3 + 1] - rows[k * 16 + p1 * 3 + 1];
      const float dz = rows[64 * 16 + p0 * 3 + 2] - rows[k * 16 + p1 * 3 + 2];
      dvals[pid] = sqrtf(dx * dx + dy * dy + dz * dz);
    }
  }
  __syncthreads();

  // ---- GRBF encode via exp-recurrence + nontemporal coalesced stores ----
  // Within a group of 4 centers spaced s: E_{k+1} = E_k * q_k,
  // q_{k+1} = q_k * rho, q_0 = exp(2s*u - s^2), rho = exp(-2 s^2).
  // u clamped at 16 so q stays finite (true values there underflow to 0).
  const float step = 20.0f / 15.0f;        // linspace(0,20,16) spacing
  const float TWO_S = 2.6666667f;          // 2*step
  const float S2 = 1.7777778f;             // step^2
  const float RHO = 0.02856550f;           // exp(-2*step^2)
  f4v* dst = (f4v*)(out + DIST_OFF) + (size_t)i * 6400;
#pragma unroll
  for (int s = 0; s < 25; s++) {
    const int f4i = t + 256 * s;  // 6400 float4 per block
    const int pair = f4i >> 2;
    const float cb0 = (float)((f4i & 3) * 4) * step;
    float u = dvals[pair] - cb0;
    u = fminf(u, 16.0f);
    float e = __expf(-u * u);
    float q = __expf(fmaf(TWO_S, u, -S2));
    f4v o;
    o.x = e;
    e *= q;           o.y = e;
    q *= RHO; e *= q; o.z = e;
    q *= RHO; e *= q; o.w = e;
    __builtin_nontemporal_store(o, dst + f4i);
  }
}

extern "C" void kernel_launch(void* const* d_in, const int* in_sizes, int n_in,
                              void* d_out, int out_size, void* d_ws, size_t ws_size,
                              hipStream_t stream) {
  const float* crd = (const float*)d_in[0];
  float* out = (float*)d_out;
  if (ws_size >= (size_t)WS_FLOATS * sizeof(float)) {
    float* ws = (float*)d_ws;
    hipLaunchKernelGGL(prep_k, dim3(NBV / 256), dim3(256), 0, stream, crd, ws);
    hipLaunchKernelGGL(fused_k<true>, dim3(NBV), dim3(256), 0, stream, crd, ws,
                       out);
  } else {
    hipLaunchKernelGGL(fused_k<false>, dim3(NBV), dim3(256), 0, stream, crd,
                       (const float*)nullptr, out);
  }
}